// Round 1
// baseline (4193.547 us; speedup 1.0000x reference)
//
#include <hip/hip_runtime.h>

#define N_NODES 50000
#define N_EDGES 1600000
#define IN_F 256
#define H1_F 128
#define H2_F 64
#define OUT_F 2
#define BN_EPS 1e-5f

// ---------------------------------------------------------------- degree
__global__ void deg_kernel(const int* __restrict__ dst, float* __restrict__ deg) {
    int stride = gridDim.x * blockDim.x;
    for (int e = blockIdx.x * blockDim.x + threadIdx.x; e < N_EDGES; e += stride)
        atomicAdd(&deg[dst[e]], 1.0f);
}

__global__ void dinv_kernel(const float* __restrict__ deg, float* __restrict__ dinv,
                            float* __restrict__ invd) {
    int i = blockIdx.x * blockDim.x + threadIdx.x;
    if (i < N_NODES) {
        float d = deg[i] + 1.0f;   // +1 self-loop
        dinv[i] = rsqrtf(d);
        invd[i] = 1.0f / d;
    }
}

__global__ void norm_kernel(const int* __restrict__ src, const int* __restrict__ dst,
                            const float* __restrict__ dinv, float* __restrict__ norm) {
    int stride = gridDim.x * blockDim.x;
    for (int e = blockIdx.x * blockDim.x + threadIdx.x; e < N_EDGES; e += stride)
        norm[e] = dinv[src[e]] * dinv[dst[e]];
}

// ---------------------------------------------------------------- fp32 GEMM  C[M,BN] = A[M,K] @ B[K,BN]
template <int BN, int TN>
__launch_bounds__(256)
__global__ void gemm_kernel(const float* __restrict__ A, const float* __restrict__ B,
                            float* __restrict__ C, int M, int K) {
    constexpr int BM = 64;
    constexpr int BK = 16;
    __shared__ float As[BM][BK + 4];   // +4 keeps rows 16B-aligned, breaks bank stride
    __shared__ float Bs[BK][BN];

    const int tid  = threadIdx.x;
    const int row0 = blockIdx.x * BM;
    const int tcol = tid & 15;   // 16 col-groups
    const int trow = tid >> 4;   // 16 row-groups of 4 rows

    float acc[4][TN];
#pragma unroll
    for (int i = 0; i < 4; ++i)
#pragma unroll
        for (int j = 0; j < TN; ++j) acc[i][j] = 0.f;

    const int arow = tid >> 2;         // 0..63
    const int acol = (tid & 3) << 2;   // 0,4,8,12
    int ar = row0 + arow;
    if (ar >= M) ar = M - 1;           // clamp (stores are guarded)

    for (int k0 = 0; k0 < K; k0 += BK) {
        float4 av = *(const float4*)(A + (size_t)ar * K + k0 + acol);
        *(float4*)(&As[arow][acol]) = av;
        constexpr int B4 = BN / 4;
#pragma unroll
        for (int l = tid; l < BK * B4; l += 256) {
            int brow = l / B4;
            int bcol = (l % B4) << 2;
            *(float4*)(&Bs[brow][bcol]) =
                *(const float4*)(B + (size_t)(k0 + brow) * BN + bcol);
        }
        __syncthreads();
#pragma unroll
        for (int kk = 0; kk < BK; ++kk) {
            float a[4];
#pragma unroll
            for (int i = 0; i < 4; ++i) a[i] = As[trow * 4 + i][kk];
            float b[TN];
#pragma unroll
            for (int j = 0; j < TN; ++j) b[j] = Bs[kk][tcol * TN + j];
#pragma unroll
            for (int i = 0; i < 4; ++i)
#pragma unroll
                for (int j = 0; j < TN; ++j) acc[i][j] += a[i] * b[j];
        }
        __syncthreads();
    }
#pragma unroll
    for (int i = 0; i < 4; ++i) {
        int r = row0 + trow * 4 + i;
        if (r < M) {
#pragma unroll
            for (int j = 0; j < TN; j += 4) {
                *(float4*)(C + (size_t)r * BN + tcol * TN + j) =
                    make_float4(acc[i][j], acc[i][j + 1], acc[i][j + 2], acc[i][j + 3]);
            }
        }
    }
}

// ---------------------------------------------------------------- agg init: agg = xw * invdeg + bias
template <int HF>
__global__ void init_kernel(const float* __restrict__ xw, const float* __restrict__ invd,
                            const float* __restrict__ bias, float* __restrict__ agg) {
    constexpr int Q = HF / 4;
    const int total  = N_NODES * Q;
    int stride = gridDim.x * blockDim.x;
    for (int idx = blockIdx.x * blockDim.x + threadIdx.x; idx < total; idx += stride) {
        int i = idx / Q;
        int q = idx & (Q - 1);
        float4 v = ((const float4*)xw)[idx];
        float  s = invd[i];
        float4 b = ((const float4*)bias)[q];
        float4 r;
        r.x = v.x * s + b.x;
        r.y = v.y * s + b.y;
        r.z = v.z * s + b.z;
        r.w = v.w * s + b.w;
        ((float4*)agg)[idx] = r;
    }
}

// ---------------------------------------------------------------- scatter-add: agg[dst] += xw[src] * norm
template <int HF>
__global__ void scatter_kernel(const int* __restrict__ src, const int* __restrict__ dst,
                               const float* __restrict__ norm, const float* __restrict__ xw,
                               float* __restrict__ agg) {
    constexpr int Q = HF / 4;           // float4 chunks per row (32 or 16)
    const long total = (long)N_EDGES * Q;
    long stride = (long)gridDim.x * blockDim.x;
    for (long idx = blockIdx.x * blockDim.x + threadIdx.x; idx < total; idx += stride) {
        int e = (int)(idx / Q);
        int q = (int)(idx & (Q - 1));
        int s = src[e];
        int d = dst[e];
        float n = norm[e];
        float4 v = ((const float4*)xw)[(size_t)s * Q + q];
        float* ap = (float*)(((float4*)agg) + ((size_t)d * Q + q));
        atomicAdd(ap + 0, v.x * n);
        atomicAdd(ap + 1, v.y * n);
        atomicAdd(ap + 2, v.z * n);
        atomicAdd(ap + 3, v.w * n);
    }
}

// ---------------------------------------------------------------- BN + ReLU (in place)
template <int HF>
__global__ void bnrelu_kernel(float* __restrict__ h, const float* __restrict__ g,
                              const float* __restrict__ be, const float* __restrict__ m,
                              const float* __restrict__ v) {
    constexpr int Q = HF / 4;
    const int total = N_NODES * Q;
    int stride = gridDim.x * blockDim.x;
    for (int idx = blockIdx.x * blockDim.x + threadIdx.x; idx < total; idx += stride) {
        int q = idx & (Q - 1);
        float4 x  = ((float4*)h)[idx];
        float4 gg = ((const float4*)g)[q];
        float4 bb = ((const float4*)be)[q];
        float4 mm = ((const float4*)m)[q];
        float4 vv = ((const float4*)v)[q];
        float4 r;
        r.x = (x.x - mm.x) * rsqrtf(vv.x + BN_EPS) * gg.x + bb.x;
        r.y = (x.y - mm.y) * rsqrtf(vv.y + BN_EPS) * gg.y + bb.y;
        r.z = (x.z - mm.z) * rsqrtf(vv.z + BN_EPS) * gg.z + bb.z;
        r.w = (x.w - mm.w) * rsqrtf(vv.w + BN_EPS) * gg.w + bb.w;
        r.x = fmaxf(r.x, 0.f);
        r.y = fmaxf(r.y, 0.f);
        r.z = fmaxf(r.z, 0.f);
        r.w = fmaxf(r.w, 0.f);
        ((float4*)h)[idx] = r;
    }
}

// ---------------------------------------------------------------- final linear 64 -> 2
__global__ void final_kernel(const float* __restrict__ h2, const float* __restrict__ Wl,
                             const float* __restrict__ bl, float* __restrict__ out) {
    __shared__ float w[H2_F * OUT_F];
    if (threadIdx.x < H2_F * OUT_F) w[threadIdx.x] = Wl[threadIdx.x];
    __syncthreads();
    float b0 = bl[0], b1 = bl[1];
    int stride = gridDim.x * blockDim.x;
    for (int i = blockIdx.x * blockDim.x + threadIdx.x; i < N_NODES; i += stride) {
        float a0 = b0, a1 = b1;
        const float4* row = (const float4*)(h2 + (size_t)i * H2_F);
#pragma unroll
        for (int q = 0; q < H2_F / 4; ++q) {
            float4 v = row[q];
            int f = q * 4;
            a0 += v.x * w[(f + 0) * 2 + 0];
            a1 += v.x * w[(f + 0) * 2 + 1];
            a0 += v.y * w[(f + 1) * 2 + 0];
            a1 += v.y * w[(f + 1) * 2 + 1];
            a0 += v.z * w[(f + 2) * 2 + 0];
            a1 += v.z * w[(f + 2) * 2 + 1];
            a0 += v.w * w[(f + 3) * 2 + 0];
            a1 += v.w * w[(f + 3) * 2 + 1];
        }
        out[i * 2 + 0] = a0;
        out[i * 2 + 1] = a1;
    }
}

// ---------------------------------------------------------------- launcher
extern "C" void kernel_launch(void* const* d_in, const int* in_sizes, int n_in,
                              void* d_out, int out_size, void* d_ws, size_t ws_size,
                              hipStream_t stream) {
    const float* x   = (const float*)d_in[0];
    const int*   ei  = (const int*)d_in[1];
    const float* W1  = (const float*)d_in[2];
    const float* b1  = (const float*)d_in[3];
    const float* g1  = (const float*)d_in[4];
    const float* be1 = (const float*)d_in[5];
    const float* m1  = (const float*)d_in[6];
    const float* v1  = (const float*)d_in[7];
    const float* W2  = (const float*)d_in[8];
    const float* b2  = (const float*)d_in[9];
    const float* g2  = (const float*)d_in[10];
    const float* be2 = (const float*)d_in[11];
    const float* m2  = (const float*)d_in[12];
    const float* v2  = (const float*)d_in[13];
    const float* Wl  = (const float*)d_in[14];
    const float* bl  = (const float*)d_in[15];
    float* out = (float*)d_out;

    const int* src = ei;            // edge_index[0]
    const int* dst = ei + N_EDGES;  // edge_index[1]

    // workspace layout (floats)
    float* ws   = (float*)d_ws;
    float* deg  = ws;                        // N
    float* dinv = deg  + N_NODES;            // N
    float* invd = dinv + N_NODES;            // N
    float* norm = invd + N_NODES;            // E
    float* xw1  = norm + N_EDGES;            // N*128  (reused as xw2)
    float* h1   = xw1  + (size_t)N_NODES * H1_F; // N*128 (reused as h2)
    float* xw2  = xw1;                       // N*64 alias (xw1 dead after scatter1)
    float* h2   = h1;                        // N*64 alias (h1 dead after gemm2)

    hipMemsetAsync(deg, 0, N_NODES * sizeof(float), stream);

    deg_kernel<<<1024, 256, 0, stream>>>(dst, deg);
    dinv_kernel<<<(N_NODES + 255) / 256, 256, 0, stream>>>(deg, dinv, invd);
    norm_kernel<<<1024, 256, 0, stream>>>(src, dst, dinv, norm);

    // ---- layer 1 ----
    gemm_kernel<H1_F, 8><<<(N_NODES + 63) / 64, 256, 0, stream>>>(x, W1, xw1, N_NODES, IN_F);
    init_kernel<H1_F><<<2048, 256, 0, stream>>>(xw1, invd, b1, h1);
    scatter_kernel<H1_F><<<4096, 256, 0, stream>>>(src, dst, norm, xw1, h1);
    bnrelu_kernel<H1_F><<<2048, 256, 0, stream>>>(h1, g1, be1, m1, v1);

    // ---- layer 2 ----  (xw2 aliases xw1; gemm reads h1, writes xw2)
    gemm_kernel<H2_F, 4><<<(N_NODES + 63) / 64, 256, 0, stream>>>(h1, W2, xw2, N_NODES, H1_F);
    // NOTE: h2 aliases h1 — init overwrites h1 AFTER gemm2 consumed it
    init_kernel<H2_F><<<2048, 256, 0, stream>>>(xw2, invd, b2, h2);
    scatter_kernel<H2_F><<<4096, 256, 0, stream>>>(src, dst, norm, xw2, h2);
    bnrelu_kernel<H2_F><<<2048, 256, 0, stream>>>(h2, g2, be2, m2, v2);

    // ---- final linear ----
    final_kernel<<<512, 256, 0, stream>>>(h2, Wl, bl, out);
}

// Round 2
// 474.773 us; speedup vs baseline: 8.8327x; 8.8327x over previous
//
#include <hip/hip_runtime.h>

#define N_NODES 50000
#define N_EDGES 1600000
#define IN_F 256
#define H1_F 128
#define H2_F 64
#define OUT_F 2
#define BN_EPS 1e-5f

#define SCAN_BLK 1024
#define SCAN_NB ((N_NODES + SCAN_BLK - 1) / SCAN_BLK)   // 49

// ---------------------------------------------------------------- degree count (int atomics)
__global__ void count_kernel(const int* __restrict__ dst, int* __restrict__ cnt) {
    int e = blockIdx.x * blockDim.x + threadIdx.x;
    if (e < N_EDGES) atomicAdd(&cnt[dst[e]], 1);
}

__global__ void dinv_kernel(const int* __restrict__ cnt, float* __restrict__ dinv) {
    int i = blockIdx.x * blockDim.x + threadIdx.x;
    if (i < N_NODES) dinv[i] = rsqrtf((float)cnt[i] + 1.0f);   // +1 self-loop
}

// ---------------------------------------------------------------- exclusive scan (3-phase)
__global__ void scan1_kernel(const int* __restrict__ cnt, int* __restrict__ rowptr,
                             int* __restrict__ bsum) {
    __shared__ int tmp[SCAN_BLK];
    int t = threadIdx.x;
    int i = blockIdx.x * SCAN_BLK + t;
    int v = (i < N_NODES) ? cnt[i] : 0;
    tmp[t] = v;
    __syncthreads();
    for (int off = 1; off < SCAN_BLK; off <<= 1) {
        int add = (t >= off) ? tmp[t - off] : 0;
        __syncthreads();
        tmp[t] += add;
        __syncthreads();
    }
    if (i < N_NODES) rowptr[i] = tmp[t] - v;          // local exclusive
    if (t == SCAN_BLK - 1) bsum[blockIdx.x] = tmp[t]; // block total
}

__global__ void scan2_kernel(const int* __restrict__ bsum, int* __restrict__ boff) {
    if (threadIdx.x == 0) {
        int acc = 0;
        for (int b = 0; b < SCAN_NB; ++b) { boff[b] = acc; acc += bsum[b]; }
    }
}

__global__ void scan3_kernel(int* __restrict__ rowptr, const int* __restrict__ boff,
                             int* __restrict__ cursor) {
    int i = blockIdx.x * blockDim.x + threadIdx.x;
    if (i < N_NODES) {
        int val = rowptr[i] + boff[i / SCAN_BLK];
        rowptr[i] = val;
        cursor[i] = val;
    }
    if (i == N_NODES) rowptr[N_NODES] = N_EDGES;
}

// ---------------------------------------------------------------- CSR fill (permute src by dst)
__global__ void fill_kernel(const int* __restrict__ src, const int* __restrict__ dst,
                            int* __restrict__ cursor, int* __restrict__ perm) {
    int e = blockIdx.x * blockDim.x + threadIdx.x;
    if (e < N_EDGES) {
        int slot = atomicAdd(&cursor[dst[e]], 1);
        perm[slot] = src[e];
    }
}

// ---------------------------------------------------------------- fp32 GEMM  C[r,c] = (A@B)[r,c] * dscale[r]
template <int BN, int TN>
__launch_bounds__(256)
__global__ void gemm_kernel(const float* __restrict__ A, const float* __restrict__ B,
                            const float* __restrict__ dscale, float* __restrict__ C,
                            int M, int K) {
    constexpr int BM = 64;
    constexpr int BK = 16;
    __shared__ float As[BM][BK + 4];
    __shared__ float Bs[BK][BN];

    const int tid  = threadIdx.x;
    const int row0 = blockIdx.x * BM;
    const int tcol = tid & 15;
    const int trow = tid >> 4;

    float acc[4][TN];
#pragma unroll
    for (int i = 0; i < 4; ++i)
#pragma unroll
        for (int j = 0; j < TN; ++j) acc[i][j] = 0.f;

    const int arow = tid >> 2;
    const int acol = (tid & 3) << 2;
    int ar = row0 + arow;
    if (ar >= M) ar = M - 1;

    for (int k0 = 0; k0 < K; k0 += BK) {
        float4 av = *(const float4*)(A + (size_t)ar * K + k0 + acol);
        *(float4*)(&As[arow][acol]) = av;
        constexpr int B4 = BN / 4;
#pragma unroll
        for (int l = tid; l < BK * B4; l += 256) {
            int brow = l / B4;
            int bcol = (l % B4) << 2;
            *(float4*)(&Bs[brow][bcol]) =
                *(const float4*)(B + (size_t)(k0 + brow) * BN + bcol);
        }
        __syncthreads();
#pragma unroll
        for (int kk = 0; kk < BK; ++kk) {
            float a[4];
#pragma unroll
            for (int i = 0; i < 4; ++i) a[i] = As[trow * 4 + i][kk];
            float b[TN];
#pragma unroll
            for (int j = 0; j < TN; ++j) b[j] = Bs[kk][tcol * TN + j];
#pragma unroll
            for (int i = 0; i < 4; ++i)
#pragma unroll
                for (int j = 0; j < TN; ++j) acc[i][j] += a[i] * b[j];
        }
        __syncthreads();
    }
#pragma unroll
    for (int i = 0; i < 4; ++i) {
        int r = row0 + trow * 4 + i;
        if (r < M) {
            float ds = dscale[r];
#pragma unroll
            for (int j = 0; j < TN; j += 4) {
                *(float4*)(C + (size_t)r * BN + tcol * TN + j) =
                    make_float4(acc[i][j] * ds, acc[i][j + 1] * ds,
                                acc[i][j + 2] * ds, acc[i][j + 3] * ds);
            }
        }
    }
}

// ---------------------------------------------------------------- fused aggregation
//   y[d][f] = relu( (dinv[d] * (xw_s[d][f] + sum_{e in row(d)} xw_s[src_e][f])) * sc[f] + sh[f] )
//   sc = g*rsqrt(v+eps), sh = (b - m)*sc + be
//   FINAL: additionally out[d][k] = sum_f y[f]*Wl[f][k] + bl[k]  (wave reduce, h2 never stored)
template <int HF, bool FINAL>
__launch_bounds__(256)
__global__ void agg_kernel(const int* __restrict__ rowptr, const int* __restrict__ perm,
                           const float* __restrict__ xw, const float* __restrict__ dinv,
                           const float* __restrict__ bias,
                           const float* __restrict__ g, const float* __restrict__ be,
                           const float* __restrict__ m, const float* __restrict__ v,
                           const float* __restrict__ Wl, const float* __restrict__ bl,
                           float* __restrict__ out) {
    constexpr int FPL = HF / 64;   // features per lane (2 for 128, 1 for 64)
    const int wid  = (blockIdx.x * blockDim.x + threadIdx.x) >> 6;
    const int lane = threadIdx.x & 63;
    if (wid >= N_NODES) return;
    const int d = wid;

    // per-lane BN constants
    float sc[FPL], sh[FPL];
#pragma unroll
    for (int q = 0; q < FPL; ++q) {
        int f = lane * FPL + q;
        float s = g[f] * rsqrtf(v[f] + BN_EPS);
        sc[q] = s;
        sh[q] = (bias[f] - m[f]) * s + be[f];
    }

    float acc[FPL];
    // self term
    if constexpr (FPL == 2) {
        float2 t = *(const float2*)(xw + (size_t)d * HF + (lane << 1));
        acc[0] = t.x; acc[1] = t.y;
    } else {
        acc[0] = xw[(size_t)d * HF + lane];
    }

    auto gather = [&](int s) {
        if constexpr (FPL == 2) {
            float2 t = *(const float2*)(xw + (size_t)s * HF + (lane << 1));
            acc[0] += t.x; acc[1] += t.y;
        } else {
            acc[0] += xw[(size_t)s * HF + lane];
        }
    };

    const int start = rowptr[d];
    const int end   = rowptr[d + 1];
    for (int base = start; base < end; base += 64) {
        int ne = end - base;
        if (ne > 64) ne = 64;
        int pv = (base + lane < end) ? perm[base + lane] : 0;
        int j = 0;
        for (; j + 4 <= ne; j += 4) {
            int s0 = __shfl(pv, j);
            int s1 = __shfl(pv, j + 1);
            int s2 = __shfl(pv, j + 2);
            int s3 = __shfl(pv, j + 3);
            gather(s0); gather(s1); gather(s2); gather(s3);
        }
        for (; j < ne; ++j) gather(__shfl(pv, j));
    }

    const float dv = dinv[d];
    if constexpr (!FINAL) {
        float y0 = fmaxf(acc[0] * dv * sc[0] + sh[0], 0.f);
        float y1 = fmaxf(acc[1] * dv * sc[1] + sh[1], 0.f);
        *(float2*)(out + (size_t)d * HF + (lane << 1)) = make_float2(y0, y1);
    } else {
        float y = fmaxf(acc[0] * dv * sc[0] + sh[0], 0.f);
        float2 w = *(const float2*)(Wl + lane * 2);
        float p0 = y * w.x;
        float p1 = y * w.y;
#pragma unroll
        for (int off = 32; off > 0; off >>= 1) {
            p0 += __shfl_xor(p0, off);
            p1 += __shfl_xor(p1, off);
        }
        if (lane == 0) {
            out[(size_t)d * 2 + 0] = p0 + bl[0];
            out[(size_t)d * 2 + 1] = p1 + bl[1];
        }
    }
}

// ---------------------------------------------------------------- launcher
extern "C" void kernel_launch(void* const* d_in, const int* in_sizes, int n_in,
                              void* d_out, int out_size, void* d_ws, size_t ws_size,
                              hipStream_t stream) {
    const float* x   = (const float*)d_in[0];
    const int*   ei  = (const int*)d_in[1];
    const float* W1  = (const float*)d_in[2];
    const float* b1  = (const float*)d_in[3];
    const float* g1  = (const float*)d_in[4];
    const float* be1 = (const float*)d_in[5];
    const float* m1  = (const float*)d_in[6];
    const float* v1  = (const float*)d_in[7];
    const float* W2  = (const float*)d_in[8];
    const float* b2  = (const float*)d_in[9];
    const float* g2  = (const float*)d_in[10];
    const float* be2 = (const float*)d_in[11];
    const float* m2  = (const float*)d_in[12];
    const float* v2  = (const float*)d_in[13];
    const float* Wl  = (const float*)d_in[14];
    const float* bl  = (const float*)d_in[15];
    float* out = (float*)d_out;

    const int* src = ei;            // edge_index[0]
    const int* dst = ei + N_EDGES;  // edge_index[1]

    // workspace layout (all 4B units, fits prior footprint)
    int*   cnt    = (int*)d_ws;                      // N   (becomes cursor)
    int*   rowptr = cnt + N_NODES;                   // N+1
    float* dinv   = (float*)(rowptr + N_NODES + 1);  // N
    int*   perm   = (int*)(dinv + N_NODES);          // E
    float* xw     = (float*)(perm + N_EDGES);        // N*128 (layer2 reuses as N*64)
    float* h1     = xw + (size_t)N_NODES * H1_F;     // N*128
    int*   bsum   = (int*)h1;                        // scan scratch (aliases h1, dead by agg1)
    int*   boff   = bsum + ((SCAN_NB + 63) & ~63);
    int*   cursor = cnt;

    hipMemsetAsync(cnt, 0, N_NODES * sizeof(int), stream);

    count_kernel<<<(N_EDGES + 255) / 256, 256, 0, stream>>>(dst, cnt);
    dinv_kernel<<<(N_NODES + 255) / 256, 256, 0, stream>>>(cnt, dinv);
    scan1_kernel<<<SCAN_NB, SCAN_BLK, 0, stream>>>(cnt, rowptr, bsum);
    scan2_kernel<<<1, 64, 0, stream>>>(bsum, boff);
    scan3_kernel<<<(N_NODES + 256) / 256, 256, 0, stream>>>(rowptr, boff, cursor);
    fill_kernel<<<(N_EDGES + 255) / 256, 256, 0, stream>>>(src, dst, cursor, perm);

    // ---- layer 1: xw = (x@W1)*dinv[row]; h1 = BN(ReLU-fused) aggregation ----
    gemm_kernel<H1_F, 8><<<(N_NODES + 63) / 64, 256, 0, stream>>>(x, W1, dinv, xw, N_NODES, IN_F);
    agg_kernel<H1_F, false><<<(N_NODES * 64 + 255) / 256, 256, 0, stream>>>(
        rowptr, perm, xw, dinv, b1, g1, be1, m1, v1, nullptr, nullptr, h1);

    // ---- layer 2 + final linear fused ----
    gemm_kernel<H2_F, 4><<<(N_NODES + 63) / 64, 256, 0, stream>>>(h1, W2, dinv, xw, N_NODES, H1_F);
    agg_kernel<H2_F, true><<<(N_NODES * 64 + 255) / 256, 256, 0, stream>>>(
        rowptr, perm, xw, dinv, b2, g2, be2, m2, v2, Wl, bl, out);
}